// Round 20
// baseline (122.403 us; speedup 1.0000x reference)
//
#include <hip/hip_runtime.h>
#include <stdint.h>

#define DEVFN __device__ __forceinline__

typedef __attribute__((ext_vector_type(8))) __bf16 bf16x8;
typedef __attribute__((ext_vector_type(8))) short short8;
typedef __attribute__((ext_vector_type(4))) float f32x4;
typedef __attribute__((ext_vector_type(4))) unsigned int u32x4;

// Native scalar cast -> hardware v_cvt_pk_bf16_f32 (RNE). (m240)
DEVFN unsigned short f2bf(float f) {
  return __builtin_bit_cast(unsigned short, (__bf16)f);
}

// global -> LDS direct copy, 16B per lane. Dest must be linear in lane order.
DEVFN void gload_lds16(const void* g, void* l) {
  __builtin_amdgcn_global_load_lds(
      (const __attribute__((address_space(1))) void*)(uintptr_t)g,
      (__attribute__((address_space(3))) void*)(uint32_t)(uintptr_t)l,
      16, 0, 0);
}

// ---------------- prep (merged weight transposes) ----------

__global__ void k_prep(const float* __restrict__ wqkv, const float* __restrict__ wout,
                       short* __restrict__ Wqt, short* __restrict__ Wot) {
  int i = blockIdx.x * blockDim.x + threadIdx.x;
  if (i < 589824) {                       // Wqt[c][r] = wqkv[r][c], 384x1536
    int c = i / 384, r = i - c * 384;
    Wqt[i] = (short)f2bf(wqkv[(size_t)r * 1536 + c]);
  } else {
    int j = i - 589824;                   // Wot[c][r] = wout[r][c], 512x384
    if (j < 196608) {
      int c = j / 512, r = j - c * 512;
      Wot[j] = (short)f2bf(wout[(size_t)r * 384 + c]);
    }
  }
}

// ---------------- GEMM1 (fused f32->bf16 A-cast): QKV = X * Wqt^T ----------
// 512 threads, 8 waves (2M x 4N of 64x64), 128x256 tile, 72KB 3-buffer LDS,
// counted vmcnt, T1+T2 swizzles. (r19 verified best; 2-phase family at its
// config-insensitive ceiling — r15/r18/r19 all within +-5%.)

#define LOADA(A0, A1, T)                                                     \
  do {                                                                       \
    const float* bA = X + (size_t)(m0 + rowA) * 384 + (T) * 32 + slA * 8;    \
    A0 = *(const f32x4*)bA;                                                  \
    A1 = *(const f32x4*)(bA + 4);                                            \
  } while (0)

#define WRITEA(BUF, A0, A1)                                                  \
  do {                                                                       \
    u32x4 w0_;                                                               \
    w0_[0] = (unsigned)f2bf(A0[0]) | ((unsigned)f2bf(A0[1]) << 16);          \
    w0_[1] = (unsigned)f2bf(A0[2]) | ((unsigned)f2bf(A0[3]) << 16);          \
    w0_[2] = (unsigned)f2bf(A1[0]) | ((unsigned)f2bf(A1[1]) << 16);          \
    w0_[3] = (unsigned)f2bf(A1[2]) | ((unsigned)f2bf(A1[3]) << 16);          \
    *(u32x4*)&As[BUF][tid * 8] = w0_;                                        \
  } while (0)

#define STEP_MAIN(T, C0, C1, N0, N1)                                         \
  do {                                                                       \
    asm volatile("s_waitcnt vmcnt(2) lgkmcnt(0)" ::: "memory");              \
    __builtin_amdgcn_sched_barrier(0);                                       \
    __builtin_amdgcn_s_barrier();                                            \
    __builtin_amdgcn_sched_barrier(0);                                       \
    LOADA(N0, N1, (T) + 2);                                                  \
    stageB(((T) + 2) % 3, (T) + 2);                                          \
    WRITEA(((T) + 1) % 3, C0, C1);                                           \
    compute((T) % 3);                                                        \
  } while (0)

__global__ __launch_bounds__(512, 2)
void k_gemm1(const float* __restrict__ X, const short* __restrict__ Bt,
             unsigned short* __restrict__ Cb) {
  __shared__ short As[3][128 * 32];
  __shared__ short Bs[3][256 * 32];
  const int tid = threadIdx.x, l = tid & 63, w = tid >> 6;
  const int nwg = gridDim.x, cpx = nwg >> 3;
  const int bid = (blockIdx.x & 7) * cpx + (blockIdx.x >> 3);
  const int mt = bid / 6, nt = bid % 6;
  const int m0 = mt << 7, n0 = nt * 256;
  const int wm = (w >> 2) << 6, wn = (w & 3) << 6;
  const int rowA = tid >> 2;
  const int slA = (tid & 3) ^ ((rowA >> 1) & 3);

  f32x4 acc[4][4];
#pragma unroll
  for (int i = 0; i < 4; i++)
#pragma unroll
    for (int j = 0; j < 4; j++) acc[i][j] = (f32x4){0.f, 0.f, 0.f, 0.f};

  auto stageB = [&](int buf, int t) {
#pragma unroll
    for (int c = 0; c < 2; ++c) {
      int ch = tid + c * 512;
      int row = ch >> 2;
      int sl = (ch & 3) ^ ((row >> 1) & 3);
      gload_lds16(Bt + (size_t)(n0 + row) * 384 + t * 32 + sl * 8, &Bs[buf][ch * 8]);
    }
  };
  const int sp8 = (((l >> 4) ^ ((l >> 1) & 3)) << 3);
  auto compute = [&](int buf) {
    bf16x8 af[4], bfr[4];
#pragma unroll
    for (int i = 0; i < 4; i++)
      af[i] = *(const bf16x8*)&As[buf][(wm + i * 16 + (l & 15)) * 32 + sp8];
#pragma unroll
    for (int j = 0; j < 4; j++)
      bfr[j] = *(const bf16x8*)&Bs[buf][(wn + j * 16 + (l & 15)) * 32 + sp8];
#pragma unroll
    for (int i = 0; i < 4; i++)
#pragma unroll
      for (int j = 0; j < 4; j++)
        acc[i][j] = __builtin_amdgcn_mfma_f32_16x16x32_bf16(af[i], bfr[j], acc[i][j], 0, 0, 0);
  };

  f32x4 a0_, a1_, b0_, b1_;
  LOADA(a0_, a1_, 0);
  LOADA(b0_, b1_, 1);
  stageB(0, 0);
  stageB(1, 1);
  asm volatile("s_waitcnt vmcnt(6)" ::: "memory");  // drain A(0)
  WRITEA(0, a0_, a1_);

#pragma unroll 1
  for (int tp = 0; tp < 10; tp += 2) {
    STEP_MAIN(tp,     b0_, b1_, a0_, a1_);
    STEP_MAIN(tp + 1, a0_, a1_, b0_, b1_);
  }
  asm volatile("s_waitcnt vmcnt(2) lgkmcnt(0)" ::: "memory");
  __builtin_amdgcn_sched_barrier(0);
  __builtin_amdgcn_s_barrier();
  __builtin_amdgcn_sched_barrier(0);
  WRITEA(2, b0_, b1_);
  compute(1);
  asm volatile("s_waitcnt vmcnt(0) lgkmcnt(0)" ::: "memory");
  __builtin_amdgcn_sched_barrier(0);
  __builtin_amdgcn_s_barrier();
  __builtin_amdgcn_sched_barrier(0);
  compute(2);

#pragma unroll
  for (int i = 0; i < 4; i++) {
    int mrow = m0 + wm + i * 16 + ((l >> 4) << 2);
#pragma unroll
    for (int j = 0; j < 4; j++) {
      int ncol = n0 + wn + j * 16 + (l & 15);
#pragma unroll
      for (int r = 0; r < 4; r++)
        Cb[(size_t)(mrow + r) * 1536 + ncol] = f2bf(acc[i][j][r]);
    }
  }
}

// ---------------- GEMM2: out = O * Wot^T + bias ----------------------------
// NEW geometry: 128x384 tile (FULL N) -> grid 256 = EXACTLY 1 block/CU,
// zero load-imbalance tail (the 384-block version had 128 CUs doing 2 blocks
// and 128 doing 1 -> ~33% idle second half-generation). 512 threads, 8 waves
// of 64x96 (acc 4x6). LDS 96KB 3-buffer. Stage = 4 uniform loads/thread
// (A:1, B:3) -> steady vmcnt(4). T1 swizzle trivially valid (grid%8==0);
// T2 sp8 formula valid since wn=96*(w&3) is a multiple of 16.
// M=32768, N=384, K=512 hardcoded.

__global__ __launch_bounds__(512, 1)
void k_gemm2(const short* __restrict__ A, const short* __restrict__ Bt,
             float* __restrict__ Cf, const float* __restrict__ bias) {
  __shared__ short As[3][128 * 32];
  __shared__ short Bs[3][384 * 32];
  const int tid = threadIdx.x;
  const int l = tid & 63, w = tid >> 6;
  const int nwg = gridDim.x, cpx = nwg >> 3;
  const int bid = (blockIdx.x & 7) * cpx + (blockIdx.x >> 3);
  const int m0 = bid << 7;                 // ntile == 1 (full N per block)
  const int wm = (w >> 2) << 6, wn = (w & 3) * 96;

  f32x4 acc[4][6];
#pragma unroll
  for (int i = 0; i < 4; i++)
#pragma unroll
    for (int j = 0; j < 6; j++) acc[i][j] = (f32x4){0.f, 0.f, 0.f, 0.f};

  const int nsteps = 16;  // K=512 / 32

  auto stage = [&](int buf, int t) {
    {
      int ch = tid;                        // A: 512 chunks = 128 rows x 4 slots
      int row = ch >> 2;
      int sl = (ch & 3) ^ ((row >> 1) & 3);
      gload_lds16(A + (size_t)(m0 + row) * 512 + t * 32 + sl * 8, &As[buf][ch * 8]);
    }
#pragma unroll
    for (int c = 0; c < 3; ++c) {
      int ch = tid + c * 512;              // B: 1536 chunks = 384 rows x 4 slots
      int row = ch >> 2;
      int sl = (ch & 3) ^ ((row >> 1) & 3);
      gload_lds16(Bt + (size_t)row * 512 + t * 32 + sl * 8, &Bs[buf][ch * 8]);
    }
  };
  const int sp8 = (((l >> 4) ^ ((l >> 1) & 3)) << 3);
  auto compute = [&](int buf) {
    bf16x8 af[4], bfr[6];
#pragma unroll
    for (int i = 0; i < 4; i++)
      af[i] = *(const bf16x8*)&As[buf][(wm + i * 16 + (l & 15)) * 32 + sp8];
#pragma unroll
    for (int j = 0; j < 6; j++)
      bfr[j] = *(const bf16x8*)&Bs[buf][(wn + j * 16 + (l & 15)) * 32 + sp8];
#pragma unroll
    for (int i = 0; i < 4; i++)
#pragma unroll
      for (int j = 0; j < 6; j++)
        acc[i][j] = __builtin_amdgcn_mfma_f32_16x16x32_bf16(af[i], bfr[j], acc[i][j], 0, 0, 0);
  };

  stage(0, 0);
  stage(1, 1);
#pragma unroll 1
  for (int t = 0; t < nsteps; ++t) {
    if (t + 1 < nsteps) {
      asm volatile("s_waitcnt vmcnt(4)" ::: "memory");  // drain stage(t)'s 4 loads
    } else {
      asm volatile("s_waitcnt vmcnt(0)" ::: "memory");
    }
    __builtin_amdgcn_sched_barrier(0);
    __builtin_amdgcn_s_barrier();
    __builtin_amdgcn_sched_barrier(0);
    if (t + 2 < nsteps) stage((t + 2) % 3, t + 2);
    compute(t % 3);
  }

#pragma unroll
  for (int i = 0; i < 4; i++) {
    int mrow = m0 + wm + i * 16 + ((l >> 4) << 2);
#pragma unroll
    for (int j = 0; j < 6; j++) {
      int ncol = wn + j * 16 + (l & 15);
#pragma unroll
      for (int r = 0; r < 4; r++)
        Cf[(size_t)(mrow + r) * 384 + ncol] = acc[i][j][r] + bias[ncol];
    }
  }
}

// ---------------- fused attention per (bp, head) ----------------
// Swapped QK^T + pi-permuted V, eager bf16 pack, per-kc sched_barrier
// pressure clamp, T5 setprio around MFMA clusters. (r17 verified)

__global__ __launch_bounds__(512, 2)
void k_attn(const short* __restrict__ qkv, unsigned short* __restrict__ O) {
  __shared__ short Kl[256 * 64];
  __shared__ short Vt[64 * 256];

  const int tid = threadIdx.x, l = tid & 63, w = tid >> 6;
  const int g = (l >> 4) & 3;
  const int bh = blockIdx.x;
  const int bp = bh >> 3, h = bh & 7;
  const size_t tokbase = (size_t)bp * 256 * 1536;
  const int qoff = h * 64, koff = 512 + h * 64, voff = 1024 + h * 64;

#pragma unroll
  for (int c = 0; c < 4; ++c) {
    int ch = tid + c * 512;
    int row = ch >> 3, s = ch & 7;
    int sg = s ^ (row & 7);
    gload_lds16(qkv + tokbase + (size_t)row * 1536 + koff + sg * 8, &Kl[ch * 8]);
  }
#pragma unroll
  for (int c = 0; c < 4; ++c) {
    int ch = tid + c * 512;
    int row = ch >> 3, d0 = (ch & 7) * 8;
    short8 v = *(const short8*)(qkv + tokbase + (size_t)row * 1536 + voff + d0);
    int kc = row >> 5, u = row & 31;
    int gg = (u >> 2) & 3;
    int off = ((u & 16) ? 4 : 0) + (u & 3);
#pragma unroll
    for (int j = 0; j < 8; ++j) {
      int d = d0 + j;
      int sl = (kc * 4 + gg) ^ (d & 15);
      Vt[d * 256 + sl * 8 + off] = v[j];
    }
  }
  __syncthreads();

  const float CEXP = 0.125f * 1.44269504f;

#pragma unroll 1
  for (int it = 0; it < 2; ++it) {
    const int q0 = w * 32 + it * 16;
    bf16x8 qa[2];
#pragma unroll
    for (int dc = 0; dc < 2; ++dc)
      qa[dc] = *(const bf16x8*)(qkv + tokbase + (size_t)(q0 + (l & 15)) * 1536 + qoff +
                                dc * 32 + (l >> 4) * 8);
    f32x4 s[16];
#pragma unroll
    for (int kt = 0; kt < 16; kt++) s[kt] = (f32x4){0.f, 0.f, 0.f, 0.f};
    __builtin_amdgcn_s_setprio(1);
#pragma unroll
    for (int dc = 0; dc < 2; ++dc) {
#pragma unroll
      for (int kt = 0; kt < 16; ++kt) {
        int kcol = kt * 16 + (l & 15);
        int sl = (dc * 4 + (l >> 4)) ^ (kcol & 7);
        bf16x8 kb = *(const bf16x8*)&Kl[kcol * 64 + sl * 8];
        s[kt] = __builtin_amdgcn_mfma_f32_16x16x32_bf16(kb, qa[dc], s[kt], 0, 0, 0);
      }
    }
    __builtin_amdgcn_s_setprio(0);
    float mx = s[0][0];
#pragma unroll
    for (int kt = 0; kt < 16; kt++)
#pragma unroll
      for (int r = 0; r < 4; r++) mx = fmaxf(mx, s[kt][r]);
    mx = fmaxf(mx, __shfl_xor(mx, 16, 64));
    mx = fmaxf(mx, __shfl_xor(mx, 32, 64));

    u32x4 pa[8];
    float sum = 0.f;
#pragma unroll
    for (int kc = 0; kc < 8; ++kc) {
      float p0 = exp2f((s[2 * kc][0] - mx) * CEXP);
      float p1 = exp2f((s[2 * kc][1] - mx) * CEXP);
      float p2 = exp2f((s[2 * kc][2] - mx) * CEXP);
      float p3 = exp2f((s[2 * kc][3] - mx) * CEXP);
      float p4 = exp2f((s[2 * kc + 1][0] - mx) * CEXP);
      float p5 = exp2f((s[2 * kc + 1][1] - mx) * CEXP);
      float p6 = exp2f((s[2 * kc + 1][2] - mx) * CEXP);
      float p7 = exp2f((s[2 * kc + 1][3] - mx) * CEXP);
      sum += ((p0 + p1) + (p2 + p3)) + ((p4 + p5) + (p6 + p7));
      u32x4 pw;
      pw[0] = (unsigned)f2bf(p0) | ((unsigned)f2bf(p1) << 16);
      pw[1] = (unsigned)f2bf(p2) | ((unsigned)f2bf(p3) << 16);
      pw[2] = (unsigned)f2bf(p4) | ((unsigned)f2bf(p5) << 16);
      pw[3] = (unsigned)f2bf(p6) | ((unsigned)f2bf(p7) << 16);
      pa[kc] = pw;
    }
    sum += __shfl_xor(sum, 16, 64);
    sum += __shfl_xor(sum, 32, 64);
    float rs = 1.0f / sum;

    f32x4 o[4];
#pragma unroll
    for (int dt = 0; dt < 4; dt++) o[dt] = (f32x4){0.f, 0.f, 0.f, 0.f};
#pragma unroll
    for (int kc = 0; kc < 8; ++kc) {
      bf16x8 paf = __builtin_bit_cast(bf16x8, pa[kc]);
      __builtin_amdgcn_s_setprio(1);
#pragma unroll
      for (int dt = 0; dt < 4; ++dt) {
        int d = dt * 16 + (l & 15);
        int sl = (kc * 4 + g) ^ (d & 15);
        bf16x8 vb = *(const bf16x8*)&Vt[d * 256 + sl * 8];
        o[dt] = __builtin_amdgcn_mfma_f32_16x16x32_bf16(paf, vb, o[dt], 0, 0, 0);
      }
      __builtin_amdgcn_s_setprio(0);
      __builtin_amdgcn_sched_barrier(0);
    }
    float rsq[4];
#pragma unroll
    for (int r = 0; r < 4; ++r)
      rsq[r] = __shfl(rs, (l & 48) | (g * 4 + r), 64);
#pragma unroll
    for (int dt = 0; dt < 4; dt++) {
#pragma unroll
      for (int r = 0; r < 4; r++) {
        int qrow = q0 + g * 4 + r;
        int d = dt * 16 + (l & 15);
        O[(size_t)(bp * 256 + qrow) * 512 + h * 64 + d] = f2bf(o[dt][r] * rsq[r]);
      }
    }
  }
}

// ---------------- launch ----------------

extern "C" void kernel_launch(void* const* d_in, const int* in_sizes, int n_in,
                              void* d_out, int out_size, void* d_ws, size_t ws_size,
                              hipStream_t stream) {
  const float* x    = (const float*)d_in[0];
  const float* wqkv = (const float*)d_in[1];
  const float* wout = (const float*)d_in[2];
  const float* bout = (const float*)d_in[3];
  float* out = (float*)d_out;
  char* ws = (char*)d_ws;

  short* Wot = (short*)(ws);                          //   0.39 MB [384][512]
  short* Wqt = (short*)(ws + 25559040);               //   1.18 MB [1536][384]
  unsigned short* O = (unsigned short*)(ws + 393216); //  33.55 MB [32768][512]
  short* QKV = (short*)(ws + 33947648);               // 100.66 MB [32768][1536]

  k_prep<<<3072, 256, 0, stream>>>(wqkv, wout, Wqt, Wot);
  // GEMM1 (fused cast): 128x256 tiles -> 1536 blocks (%8==0)
  k_gemm1<<<1536, 512, 0, stream>>>(x, Wqt, (unsigned short*)QKV);
  k_attn<<<1024, 512, 0, stream>>>(QKV, O);
  // GEMM2: 128x384 tiles (full N) -> 256 blocks = exactly 1/CU (%8==0)
  k_gemm2<<<256, 512, 0, stream>>>((const short*)O, Wot, out, bout);
  (void)in_sizes; (void)n_in; (void)out_size; (void)ws_size;
}